// Round 7
// baseline (196.253 us; speedup 1.0000x reference)
//
#include <hip/hip_runtime.h>
#include <stdint.h>

// Problem constants
#define BB   2048
#define DIN  2048
#define UU   1024
#define KF   49
#define GM   2048         // GEMM M = batch
#define GK   3072         // GEMM K = UU + DIN
#define GN   5120         // GEMM N = 5*UU

// GEMM block geometry
#define BM    128         // batch rows per block
#define UC    64          // unit-cols per block
#define BKS   32          // K per step
#define SZBUF 28672       // bytes per LDS buffer (A 8KB + B 20KB); 3 buffers

typedef __bf16  bf16x8 __attribute__((ext_vector_type(8)));
typedef float   f32x4  __attribute__((ext_vector_type(4)));

// inline-asm HBM load: explicit FIFO position, compiler can't reorder vs waitcnt
#define VL(dst, ptr) asm volatile("global_load_dwordx4 %0, %1, off" \
                                  : "=v"(dst) : "v"(ptr) : "memory")

static __device__ __forceinline__ unsigned short f2bf(float f) {
    union { float f; unsigned u; } x; x.f = f;
    unsigned u = x.u;
    unsigned r = (u + 0x7fffu + ((u >> 16) & 1u)) >> 16;   // RNE
    return (unsigned short)r;
}

// ---------------------------------------------------------------------------
// Kernel 1: prep = buildA (blocks [0,6144)) + buildW transpose (blocks [6144,21504))
//   A[b][k]       = bf16([h_tm | inputs])                        [GM][GK]
//   Wt2[u*5+g][k] = bf16(k<UU ? W_gates[k][g*UU+u] : U_gates[k-UU][g*UU+u])
// ---------------------------------------------------------------------------
__global__ void prep(const float* __restrict__ h, const float* __restrict__ x,
                     const float* __restrict__ Wg, const float* __restrict__ Ug,
                     unsigned short* __restrict__ A, unsigned short* __restrict__ Wt) {
    __shared__ float t[32][36];
    if (blockIdx.x < 6144) {
        int idx = blockIdx.x * 256 + threadIdx.x;    // one thread = 4 elems
        int b = idx / (GK / 4);
        int k = (idx % (GK / 4)) * 4;
        float4 v;
        if (k < UU) v = *(const float4*)(h + (size_t)b * UU + k);
        else        v = *(const float4*)(x + (size_t)b * DIN + (k - UU));
        ushort4 o;
        o.x = f2bf(v.x); o.y = f2bf(v.y); o.z = f2bf(v.z); o.w = f2bf(v.w);
        *(ushort4*)(A + (size_t)idx * 4) = o;
    } else {
        int bid2 = blockIdx.x - 6144;                // 32x32 transpose tiles
        int k0 = (bid2 % (GK / 32)) * 32;
        int n0 = (bid2 / (GK / 32)) * 32;
        int r  = threadIdx.x >> 3;                   // 0..31
        int cq = threadIdx.x & 7;                    // 0..7  (x4 floats)
        int k = k0 + r;
        const float* src = (k < UU) ? (Wg + (size_t)k * GN) : (Ug + (size_t)(k - UU) * GN);
        *(float4*)&t[r][cq * 4] = *(const float4*)(src + n0 + cq * 4);
        __syncthreads();
        int n = n0 + r;                              // original col = g*UU + u
        int u = n & (UU - 1);
        int g = n >> 10;
        ushort4 o;
        o.x = f2bf(t[cq * 4 + 0][r]);
        o.y = f2bf(t[cq * 4 + 1][r]);
        o.z = f2bf(t[cq * 4 + 2][r]);
        o.w = f2bf(t[cq * 4 + 3][r]);
        *(ushort4*)(Wt + (size_t)(u * 5 + g) * GK + k0 + cq * 4) = o;
    }
}

// ---------------------------------------------------------------------------
// Kernel 2: fused 5-gate GEMM + v_seq reduction + LSTM tail.
// FRAGMENT-ORDER LDS (rule #21: permute the global SOURCE, keep LDS dest linear):
// each 16x32 MFMA subtile is stored as 64 chunks of 16B in exact fragment order
// (chunk = subtile*64 + lane). Fragment reads become lds[base + lane*16] --
// fully sequential, zero bank conflicts (fixes the 8-way conflict of row-strided
// reads that dominated R4-R6 at ~2500 cy/iter).
// A region: 8 subtiles (rows), B region: 20 subtiles (wc*5+g). Pipeline: 3 LDS
// buffers, stage t+2 ahead, vmcnt(6), raw s_barrier (unchanged from R6).
// ---------------------------------------------------------------------------
__global__ __launch_bounds__(512, 2) void gemm_fused(
        const unsigned short* __restrict__ A, const unsigned short* __restrict__ Wt,
        const float* __restrict__ m_tm, const float* __restrict__ bg,
        const float* __restrict__ v_seq, float* __restrict__ out) {
    __shared__ __align__(16) char lds[3 * SZBUF];   // 86016 B -> 1 block/CU

    const int tid  = threadIdx.x;
    const int lane = tid & 63;
    const int wave = tid >> 6;          // 0..7
    const int wr = wave >> 2;           // 0..1 (row half)
    const int wc = wave & 3;            // 0..3 (ucol quarter)
    const int brow  = blockIdx.y * BM;
    const int ucol0 = blockIdx.x * UC;

    f32x4 acc[4][5];
#pragma unroll
    for (int m = 0; m < 4; m++)
#pragma unroll
        for (int g = 0; g < 5; g++) acc[m][g] = (f32x4){0.f, 0.f, 0.f, 0.f};

    // staging chunk map, fragment-order:
    //  A chunk j in [0,512):  s=j>>6 (row subtile), q=(j>>4)&3, r=j&15
    //     -> global row brow + s*16 + r, k-part q; LDS addr j*16
    //  B chunk j in [0,1280): sub=j>>6 (=c*5+g), q,r as above
    //     -> Wt2 row (ucol0 + c*16 + r)*5 + g, k-part q; LDS addr 8192 + j*16
    const unsigned short* src[4];
    int ldsoff[4];
#pragma unroll
    for (int t = 0; t < 4; t++) {
        if (t == 0) {
            int j = tid;
            int s = j >> 6, q = (j >> 4) & 3, r = j & 15;
            src[t] = A + (size_t)(brow + s * 16 + r) * GK + q * 8;
            ldsoff[t] = j * 16;
        } else {
            int j = (t < 3) ? (t - 1) * 512 + tid : 1024 + (tid & 255); // round 3 duplicated
            int sub = j >> 6, q = (j >> 4) & 3, r = j & 15;
            int c = sub / 5, g = sub - 5 * c;
            src[t] = Wt + (size_t)((ucol0 + c * 16 + r) * 5 + g) * GK + q * 8;
            ldsoff[t] = 8192 + j * 16;
        }
    }

    // conflict-free fragment read bases (lane*16 sequential)
    const int abase = wr * 4096 + lane * 16;                   // + m*1024
    const int bbase = 8192 + (wc * 5) * 1024 + lane * 16;      // + g*1024

    auto STAGE = [&](int kstep, int bufbase) {
        const int koff = kstep * BKS;
#pragma unroll
        for (int t = 0; t < 4; t++)
            __builtin_amdgcn_global_load_lds(
                (const __attribute__((address_space(1))) void*)(src[t] + koff),
                (__attribute__((address_space(3))) void*)(lds + bufbase + ldsoff[t]), 16, 0, 0);
    };

    auto COMPUTE = [&](int bufbase) {
        bf16x8 af[4], bfr[5];
#pragma unroll
        for (int m = 0; m < 4; m++) af[m]  = *(const bf16x8*)(lds + bufbase + abase + m * 1024);
#pragma unroll
        for (int g = 0; g < 5; g++) bfr[g] = *(const bf16x8*)(lds + bufbase + bbase + g * 1024);
#pragma unroll
        for (int m = 0; m < 4; m++)
#pragma unroll
            for (int g = 0; g < 5; g++)
                acc[m][g] = __builtin_amdgcn_mfma_f32_16x16x32_bf16(af[m], bfr[g], acc[m][g], 0, 0, 0);
    };

    // v_seq: thread covers rows (tid>>4)+{0,32,64,96}, float4-col tid&15
    const float* vp = v_seq + (size_t)(brow + (tid >> 4)) * (KF * UU) + ucol0 + (tid & 15) * 4;
    const size_t RG = (size_t)32 * KF * UU;
    f32x4 vacc0 = {0,0,0,0}, vacc1 = {0,0,0,0}, vacc2 = {0,0,0,0}, vacc3 = {0,0,0,0};
    f32x4 slA0, slA1, slB0, slB1;

    // prologue: S(0)->b0, V(0)->slA, S(1)->b1, V(1)->slB; wait S(0)+V(0); barrier
    STAGE(0, 0);
    VL(slA0, vp);
    VL(slA1, vp + RG);
    STAGE(1, SZBUF);
    VL(slB0, vp + 2 * RG);
    VL(slB1, vp + 3 * RG);
    asm volatile("s_waitcnt vmcnt(6)" ::: "memory");
    __builtin_amdgcn_s_barrier();
    __builtin_amdgcn_sched_barrier(0);

    int cb = 0;                                     // (t%3)*SZBUF for current t
    for (int tp = 0; tp < 47; ++tp) {
        {   // even t = 2tp: consume slA(k=tp); stage t+2; load slA<-k=tp+1
            vacc0 += slA0; vacc1 += slA1;
            int sb = cb + 2 * SZBUF; if (sb >= 3 * SZBUF) sb -= 3 * SZBUF;
            STAGE(2 * tp + 2, sb);
            VL(slA0, vp + (size_t)(tp + 1) * UU);
            VL(slA1, vp + RG + (size_t)(tp + 1) * UU);
            COMPUTE(cb);
            asm volatile("s_waitcnt vmcnt(6)" ::: "memory");
            __builtin_amdgcn_s_barrier();
            __builtin_amdgcn_sched_barrier(0);
            cb += SZBUF; if (cb >= 3 * SZBUF) cb = 0;
        }
        {   // odd t = 2tp+1: consume slB(k=tp); stage t+2; load slB<-k=tp+1
            vacc2 += slB0; vacc3 += slB1;
            int sb = cb + 2 * SZBUF; if (sb >= 3 * SZBUF) sb -= 3 * SZBUF;
            STAGE(2 * tp + 3, sb);
            VL(slB0, vp + 2 * RG + (size_t)(tp + 1) * UU);
            VL(slB1, vp + 3 * RG + (size_t)(tp + 1) * UU);
            COMPUTE(cb);
            asm volatile("s_waitcnt vmcnt(6)" ::: "memory");
            __builtin_amdgcn_s_barrier();
            __builtin_amdgcn_sched_barrier(0);
            cb += SZBUF; if (cb >= 3 * SZBUF) cb = 0;
        }
    }
    // t = 94 (cb = SZBUF): consume slA(k=47); no stage/vl; drain all
    vacc0 += slA0; vacc1 += slA1;
    COMPUTE(cb);
    asm volatile("s_waitcnt vmcnt(0)" ::: "memory");
    __builtin_amdgcn_s_barrier();
    __builtin_amdgcn_sched_barrier(0);
    cb += SZBUF; if (cb >= 3 * SZBUF) cb = 0;
    // t = 95 (cb = 2*SZBUF): consume slB(k=47)
    vacc2 += slB0; vacc3 += slB1;
    COMPUTE(cb);

    // leftover v_seq k = 48 (plain loads; pipeline drained)
    {
        const float4 w0 = *(const float4*)(vp + (size_t)48 * UU);
        const float4 w1 = *(const float4*)(vp + RG + (size_t)48 * UU);
        const float4 w2 = *(const float4*)(vp + 2 * RG + (size_t)48 * UU);
        const float4 w3 = *(const float4*)(vp + 3 * RG + (size_t)48 * UU);
        vacc0.x += w0.x; vacc0.y += w0.y; vacc0.z += w0.z; vacc0.w += w0.w;
        vacc1.x += w1.x; vacc1.y += w1.y; vacc1.z += w1.z; vacc1.w += w1.w;
        vacc2.x += w2.x; vacc2.y += w2.y; vacc2.z += w2.z; vacc2.w += w2.w;
        vacc3.x += w3.x; vacc3.y += w3.y; vacc3.z += w3.z; vacc3.w += w3.w;
    }

    // exchange v-sums via LDS: lv[128][68] floats (34.8KB; buffers free now)
    float* lv = (float*)lds;
    {
        const int xr = tid >> 4, xc = (tid & 15) * 4;
        *(f32x4*)&lv[(size_t)(xr +  0) * 68 + xc] = vacc0;
        *(f32x4*)&lv[(size_t)(xr + 32) * 68 + xc] = vacc1;
        *(f32x4*)&lv[(size_t)(xr + 64) * 68 + xc] = vacc2;
        *(f32x4*)&lv[(size_t)(xr + 96) * 68 + xc] = vacc3;
    }
    __syncthreads();

    // Epilogue: gates + cell + sentinel + ct, write 3 outputs.
    const int ucol = ucol0 + wc * 16 + (lane & 15);
    const int lcol = wc * 16 + (lane & 15);
    const float b0 = bg[0 * UU + ucol];
    const float b1 = bg[1 * UU + ucol];
    const float b2 = bg[2 * UU + ucol];
    const float b3 = bg[3 * UU + ucol];
    const float b4 = bg[4 * UU + ucol];
    const int lr0 = wr * 64 + ((lane >> 4) << 2);
    float* out0 = out;
    float* out1 = out + (size_t)GM * UU;
    float* out2 = out + 2 * (size_t)GM * UU;
#pragma unroll
    for (int m = 0; m < 4; m++) {
#pragma unroll
        for (int j = 0; j < 4; j++) {
            const int lrow = lr0 + m * 16 + j;
            const int row  = brow + lrow;
            const size_t idx = (size_t)row * UU + ucol;
            const float vs  = lv[(size_t)lrow * 68 + lcol];
            const float mtm = m_tm[idx];
            const float f = acc[m][0][j] + b0;
            const float i = acc[m][1][j] + b1;
            const float o = acc[m][2][j] + b2;
            const float g = acc[m][3][j] + b3;
            const float a = acc[m][4][j] + b4;
            const float ft = 1.f / (1.f + __expf(-f));
            const float it = 1.f / (1.f + __expf(-i));
            const float ot = 1.f / (1.f + __expf(-o));
            const float gt = 1.f / (1.f + __expf(-g));
            const float at = tanhf(a);
            const float mtv = mtm * ft + it * at;
            const float tm  = tanhf(mtv);
            const float ht  = ot * tm;
            const float st  = gt * tm;
            out0[idx] = ht + vs + st;
            out1[idx] = ht;
            out2[idx] = mtv;
        }
    }
}

// ---------------------------------------------------------------------------
extern "C" void kernel_launch(void* const* d_in, const int* in_sizes, int n_in,
                              void* d_out, int out_size, void* d_ws, size_t ws_size,
                              hipStream_t stream) {
    (void)in_sizes; (void)n_in; (void)out_size; (void)ws_size;
    const float* inputs  = (const float*)d_in[0];
    const float* h_tm    = (const float*)d_in[1];
    const float* m_tm    = (const float*)d_in[2];
    const float* v_seq   = (const float*)d_in[3];
    const float* W_gates = (const float*)d_in[4];
    const float* U_gates = (const float*)d_in[5];
    const float* b_gates = (const float*)d_in[6];
    // d_in[7..9] (W_z, U_z, W_h) are dead: softmax over a size-1 axis == 1.

    char* ws = (char*)d_ws;
    unsigned short* Abf = (unsigned short*)ws;                  // 2048*3072*2 = 12,582,912 B
    unsigned short* Wt  = (unsigned short*)(ws + 12582912);     // 5120*3072*2 = 31,457,280 B
    float* out = (float*)d_out;

    hipLaunchKernelGGL(prep, dim3(6144 + (GK / 32) * (GN / 32)), dim3(256), 0, stream,
                       h_tm, inputs, W_gates, U_gates, Abf, Wt);
    hipLaunchKernelGGL(gemm_fused, dim3(UU / UC, GM / BM), dim3(512), 0, stream,
                       Abf, Wt, m_tm, b_gates, v_seq, out);
}

// Round 8
// 188.438 us; speedup vs baseline: 1.0415x; 1.0415x over previous
//
#include <hip/hip_runtime.h>
#include <stdint.h>

// Problem constants
#define BB   2048
#define DIN  2048
#define UU   1024
#define KF   49
#define GM   2048         // GEMM M = batch
#define GK   3072         // GEMM K = UU + DIN
#define GN   5120         // GEMM N = 5*UU

#define BM    128         // batch rows per block
#define UC    64          // unit-cols per block

typedef __bf16  bf16x8 __attribute__((ext_vector_type(8)));
typedef float   f32x4  __attribute__((ext_vector_type(4)));
typedef unsigned short u16x8 __attribute__((ext_vector_type(8)));

static __device__ __forceinline__ unsigned short f2bf(float f) {
    union { float f; unsigned u; } x; x.f = f;
    unsigned u = x.u;
    unsigned r = (u + 0x7fffu + ((u >> 16) & 1u)) >> 16;   // RNE
    return (unsigned short)r;
}

// ---------------------------------------------------------------------------
// Kernel 1: prep — builds FRAGMENT-ORDER permuted operands in global memory:
//  A_perm[rb][t][j]  (16B chunks): j = s*64 + q*16 + r holds
//      A[row = rb*128 + s*16 + r][k = t*32 + q*8 .. +8]   (A = [h_tm | inputs])
//  Wt_perm[cb][t][j]: j = (c*5+g)*64 + q*16 + rr holds
//      W-col (g*1024 + cb*64 + c*16 + rr), k = t*32 + q*8 .. +8
//  With this layout the GEMM's per-lane fragment load is base + lane*16:
//  fully coalesced global reads, zero LDS in the main loop.
// Blocks [0,3072): A part (1 thread = 1 chunk). Blocks [3072, 18432): Wt part
// (32x32 LDS transpose tiles, k0 = tile k-range = exactly one k-step).
// ---------------------------------------------------------------------------
__global__ void prep(const float* __restrict__ h, const float* __restrict__ x,
                     const float* __restrict__ Wg, const float* __restrict__ Ug,
                     unsigned short* __restrict__ A, unsigned short* __restrict__ Wt) {
    __shared__ float t[32][36];
    if (blockIdx.x < 3072) {
        int cid = blockIdx.x * 256 + threadIdx.x;     // chunk id, < 786432
        int rb  = cid / 49152;                        // 96*512
        int rem = cid - rb * 49152;
        int ts  = rem >> 9;
        int j   = rem & 511;
        int s = j >> 6, q = (j >> 4) & 3, r = j & 15;
        int row = rb * 128 + s * 16 + r;
        int k   = ts * 32 + q * 8;
        const float* srcp = (k < UU) ? (h + (size_t)row * UU + k)
                                     : (x + (size_t)row * DIN + (k - UU));
        float4 lo = *(const float4*)(srcp);
        float4 hi = *(const float4*)(srcp + 4);
        u16x8 o;
        o[0] = f2bf(lo.x); o[1] = f2bf(lo.y); o[2] = f2bf(lo.z); o[3] = f2bf(lo.w);
        o[4] = f2bf(hi.x); o[5] = f2bf(hi.y); o[6] = f2bf(hi.z); o[7] = f2bf(hi.w);
        *(u16x8*)(A + (size_t)cid * 8) = o;           // coalesced 16B stores
    } else {
        int bid2 = blockIdx.x - 3072;                 // 96 x 160 tiles
        int k0 = (bid2 % 96) * 32;
        int n0 = (bid2 / 96) * 32;
        int r  = threadIdx.x >> 3;                    // 0..31
        int cq = threadIdx.x & 7;                     // 0..7 (x4 floats)
        int k = k0 + r;
        const float* src = (k < UU) ? (Wg + (size_t)k * GN) : (Ug + (size_t)(k - UU) * GN);
        *(float4*)&t[r][cq * 4] = *(const float4*)(src + n0 + cq * 4);
        __syncthreads();
        int n = n0 + r;                               // original col = g*1024 + u
        int g = n >> 10;
        int u = n & (UU - 1);
        int cb = u >> 6, c = (u >> 4) & 3, rr = u & 15;
        int tstep = k0 >> 5;
        int q = cq >> 1, half = cq & 1;
        int jch = (c * 5 + g) * 64 + q * 16 + rr;
        size_t off = (size_t)cb * (96 * 1280 * 8) + (size_t)tstep * (1280 * 8)
                   + (size_t)jch * 8 + half * 4;      // ushort units
        ushort4 o;
        o.x = f2bf(t[cq * 4 + 0][r]);
        o.y = f2bf(t[cq * 4 + 1][r]);
        o.z = f2bf(t[cq * 4 + 2][r]);
        o.w = f2bf(t[cq * 4 + 3][r]);
        *(ushort4*)(Wt + off) = o;
    }
}

// ---------------------------------------------------------------------------
// Kernel 2: BARRIER-FREE fused 5-gate GEMM + v_seq reduction + LSTM tail.
// Operands are fragment-order in global: each wave loads its MFMA fragments
// straight to registers (base + lane*16, coalesced), no LDS / no barriers in
// the K-loop. 8 waves free-run with depth-1 register double-buffering; the CU
// scheduler overlaps waves (VMEM vs MFMA pipes). Single __syncthreads() at the
// end for the v-sum LDS exchange.
// grid = (16,16), block = 512 (8 waves: wr = wave>>2, wc = wave&3).
// ---------------------------------------------------------------------------
__global__ __launch_bounds__(512, 2) void gemm_fused(
        const unsigned short* __restrict__ A, const unsigned short* __restrict__ Wt,
        const float* __restrict__ m_tm, const float* __restrict__ bg,
        const float* __restrict__ v_seq, float* __restrict__ out) {
    __shared__ float lv[128 * 68];                    // epilogue exchange only

    const int tid  = threadIdx.x;
    const int lane = tid & 63;
    const int wave = tid >> 6;
    const int wr = wave >> 2;           // 0..1 (row half)
    const int wc = wave & 3;            // 0..3 (ucol quarter)
    const int brow  = blockIdx.y * BM;
    const int ucol0 = blockIdx.x * UC;

    f32x4 acc[4][5];
#pragma unroll
    for (int m = 0; m < 4; m++)
#pragma unroll
        for (int g = 0; g < 5; g++) acc[m][g] = (f32x4){0.f, 0.f, 0.f, 0.f};

    // fragment pointers (byte): A chunk (wr*4+m)*64+lane; B chunk (wc*5+g)*64+lane
    const char* pA = (const char*)A + ((size_t)blockIdx.y * (96 * 512)
                                       + (size_t)(wr * 4) * 64 + lane) * 16;
    const char* pB = (const char*)Wt + ((size_t)blockIdx.x * (96 * 1280)
                                        + (size_t)(wc * 5) * 64 + lane) * 16;

    // v_seq: thread covers rows (tid>>4)+{0,32,64,96}, float4-col tid&15
    const float* vp = v_seq + (size_t)(brow + (tid >> 4)) * (KF * UU) + ucol0 + (tid & 15) * 4;
    const size_t RG = (size_t)32 * KF * UU;
    f32x4 vacc0 = {0,0,0,0}, vacc1 = {0,0,0,0}, vacc2 = {0,0,0,0}, vacc3 = {0,0,0,0};

    bf16x8 a0[4], b0[5], a1[4], b1[5];
    f32x4 slA0, slA1, slB0, slB1;

    // prologue: operands for t=0; v k=0 for all 4 row-groups
#pragma unroll
    for (int m = 0; m < 4; m++) a0[m] = *(const bf16x8*)(pA + m * 1024);
#pragma unroll
    for (int g = 0; g < 5; g++) b0[g] = *(const bf16x8*)(pB + g * 1024);
    slA0 = *(const f32x4*)(vp);
    slA1 = *(const f32x4*)(vp + RG);
    slB0 = *(const f32x4*)(vp + 2 * RG);
    slB1 = *(const f32x4*)(vp + 3 * RG);

    size_t ao = 8192, bo = 20480;       // byte offsets of "next" k-step
    for (int tp = 0; tp < 48; ++tp) {
        {   // even t = 2tp: compute set0, load set1 (t+1); consume slA(k=tp)
#pragma unroll
            for (int m = 0; m < 4; m++) a1[m] = *(const bf16x8*)(pA + ao + m * 1024);
#pragma unroll
            for (int g = 0; g < 5; g++) b1[g] = *(const bf16x8*)(pB + bo + g * 1024);
            vacc0 += slA0; vacc1 += slA1;
            if (tp < 47) {
                slA0 = *(const f32x4*)(vp + (size_t)(tp + 1) * UU);
                slA1 = *(const f32x4*)(vp + RG + (size_t)(tp + 1) * UU);
            }
#pragma unroll
            for (int m = 0; m < 4; m++)
#pragma unroll
                for (int g = 0; g < 5; g++)
                    acc[m][g] = __builtin_amdgcn_mfma_f32_16x16x32_bf16(a0[m], b0[g], acc[m][g], 0, 0, 0);
            ao += 8192; bo += 20480;
        }
        {   // odd t = 2tp+1: compute set1, load set0 (t+1 if exists); consume slB(k=tp)
            if (tp < 47) {
#pragma unroll
                for (int m = 0; m < 4; m++) a0[m] = *(const bf16x8*)(pA + ao + m * 1024);
#pragma unroll
                for (int g = 0; g < 5; g++) b0[g] = *(const bf16x8*)(pB + bo + g * 1024);
            }
            vacc2 += slB0; vacc3 += slB1;
            if (tp < 47) {
                slB0 = *(const f32x4*)(vp + 2 * RG + (size_t)(tp + 1) * UU);
                slB1 = *(const f32x4*)(vp + 3 * RG + (size_t)(tp + 1) * UU);
            }
#pragma unroll
            for (int m = 0; m < 4; m++)
#pragma unroll
                for (int g = 0; g < 5; g++)
                    acc[m][g] = __builtin_amdgcn_mfma_f32_16x16x32_bf16(a1[m], b1[g], acc[m][g], 0, 0, 0);
            ao += 8192; bo += 20480;
        }
    }

    // leftover v_seq k = 48
    {
        const f32x4 w0 = *(const f32x4*)(vp + (size_t)48 * UU);
        const f32x4 w1 = *(const f32x4*)(vp + RG + (size_t)48 * UU);
        const f32x4 w2 = *(const f32x4*)(vp + 2 * RG + (size_t)48 * UU);
        const f32x4 w3 = *(const f32x4*)(vp + 3 * RG + (size_t)48 * UU);
        vacc0 += w0; vacc1 += w1; vacc2 += w2; vacc3 += w3;
    }

    // exchange v-sums via LDS: lv[row][col], row stride 68 floats
    {
        const int xr = tid >> 4, xc = (tid & 15) * 4;
        *(f32x4*)&lv[(size_t)(xr +  0) * 68 + xc] = vacc0;
        *(f32x4*)&lv[(size_t)(xr + 32) * 68 + xc] = vacc1;
        *(f32x4*)&lv[(size_t)(xr + 64) * 68 + xc] = vacc2;
        *(f32x4*)&lv[(size_t)(xr + 96) * 68 + xc] = vacc3;
    }
    __syncthreads();

    // Epilogue: gates + cell + sentinel + ct, write 3 outputs.
    const int ucol = ucol0 + wc * 16 + (lane & 15);
    const int lcol = wc * 16 + (lane & 15);
    const float c0 = bg[0 * UU + ucol];
    const float c1 = bg[1 * UU + ucol];
    const float c2 = bg[2 * UU + ucol];
    const float c3 = bg[3 * UU + ucol];
    const float c4 = bg[4 * UU + ucol];
    const int lr0 = wr * 64 + ((lane >> 4) << 2);
    float* out0 = out;
    float* out1 = out + (size_t)GM * UU;
    float* out2 = out + 2 * (size_t)GM * UU;
#pragma unroll
    for (int m = 0; m < 4; m++) {
#pragma unroll
        for (int j = 0; j < 4; j++) {
            const int lrow = lr0 + m * 16 + j;
            const int row  = brow + lrow;
            const size_t idx = (size_t)row * UU + ucol;
            const float vs  = lv[(size_t)lrow * 68 + lcol];
            const float mtm = m_tm[idx];
            const float f = acc[m][0][j] + c0;
            const float i = acc[m][1][j] + c1;
            const float o = acc[m][2][j] + c2;
            const float g = acc[m][3][j] + c3;
            const float a = acc[m][4][j] + c4;
            const float ft = 1.f / (1.f + __expf(-f));
            const float it = 1.f / (1.f + __expf(-i));
            const float ot = 1.f / (1.f + __expf(-o));
            const float gt = 1.f / (1.f + __expf(-g));
            const float at = tanhf(a);
            const float mtv = mtm * ft + it * at;
            const float tm  = tanhf(mtv);
            const float ht  = ot * tm;
            const float st  = gt * tm;
            out0[idx] = ht + vs + st;
            out1[idx] = ht;
            out2[idx] = mtv;
        }
    }
}

// ---------------------------------------------------------------------------
extern "C" void kernel_launch(void* const* d_in, const int* in_sizes, int n_in,
                              void* d_out, int out_size, void* d_ws, size_t ws_size,
                              hipStream_t stream) {
    (void)in_sizes; (void)n_in; (void)out_size; (void)ws_size;
    const float* inputs  = (const float*)d_in[0];
    const float* h_tm    = (const float*)d_in[1];
    const float* m_tm    = (const float*)d_in[2];
    const float* v_seq   = (const float*)d_in[3];
    const float* W_gates = (const float*)d_in[4];
    const float* U_gates = (const float*)d_in[5];
    const float* b_gates = (const float*)d_in[6];
    // d_in[7..9] (W_z, U_z, W_h) are dead: softmax over a size-1 axis == 1.

    char* ws = (char*)d_ws;
    unsigned short* Abf = (unsigned short*)ws;                  // A_perm: 12,582,912 B
    unsigned short* Wt  = (unsigned short*)(ws + 12582912);     // Wt_perm: 31,457,280 B
    float* out = (float*)d_out;

    hipLaunchKernelGGL(prep, dim3(3072 + 96 * (GN / 32)), dim3(256), 0, stream,
                       h_tm, inputs, W_gates, U_gates, Abf, Wt);
    hipLaunchKernelGGL(gemm_fused, dim3(UU / UC, GM / BM), dim3(512), 0, stream,
                       Abf, Wt, m_tm, b_gates, v_seq, out);
}